// Round 9
// baseline (333.884 us; speedup 1.0000x reference)
//
#include <hip/hip_runtime.h>
#include <hip/hip_cooperative_groups.h>
#include <math.h>

namespace cg = cooperative_groups;

// ---- problem constants ----
#define DIMC   256
#define HID    680
#define CHN    1360
#define HP     14
#define WP     14
#define P      196
#define POSI   4
#define INTER  64
#define BATCH  64
#define KPAD   704          // 680 padded to 22*32
#define OUTCH  12240        // CHN*9
#define MW     1408         // per-k-plane channel pad
#define MTOT   12672        // 9*MW
#define KIM    576          // INTER*9
#define MPADIN 1408         // 1360 padded to 11*128
#define EPSLN  1e-5f

typedef __attribute__((ext_vector_type(8))) short short8;
typedef __attribute__((ext_vector_type(4))) short short4v;
typedef __attribute__((ext_vector_type(4))) float f32x4;

// ---- workspace layout (bytes) ----
#define OFS_WBIN  0u                  // 1408*256*2   = 720896
#define OFS_WBOUT 720896u             // 256*704*2    = 360448
#define OFS_XT    1081344u            // 64*196*256*2 = 6422528
#define OFS_ABUF  7503872u            // 12544*4
#define OFS_A2BUF 7554048u            // 12544*4
#define OFS_RED   7604224u            // 512*4 partials
#define OFS_WGTT  7606272u            // 196*9*1360*2 = 4798080  ([p][k][ch])
#define OFS_H1T   12404352u           // 64*196*1360*2 = 34127872
#define OFS_HGT   46532224u           // 64*196*704*2  = 17661952
#define OFS_IMC   64194176u           // 196*576*2     = 225792   (end ~64.4MB)

__device__ __forceinline__ unsigned short f2bf(float f) {
    union { float f; unsigned u; } v; v.f = f;
    unsigned u = v.u;
    return (unsigned short)((u + 0x7FFFu + ((u >> 16) & 1u)) >> 16);   // RNE
}
__device__ __forceinline__ float bf2f(unsigned short h) {
    union { unsigned u; float f; } v; v.u = ((unsigned)h) << 16; return v.f;
}

// async 16B global->LDS (wave-uniform LDS base + lane*16; global src may be per-lane)
__device__ __forceinline__ void gl2lds16(const unsigned short* g, unsigned short* l) {
    __builtin_amdgcn_global_load_lds(
        (const __attribute__((address_space(1))) unsigned int*)g,
        (__attribute__((address_space(3))) unsigned int*)l, 16, 0, 0);
}
__device__ __forceinline__ void gl2lds16f(const float* g, float* l) {
    __builtin_amdgcn_global_load_lds(
        (const __attribute__((address_space(1))) unsigned int*)g,
        (__attribute__((address_space(3))) unsigned int*)l, 16, 0, 0);
}
// BK=32 tile: row stride 32, 4 slots, rotate by row>>1
__device__ __forceinline__ short8 fragld(const unsigned short* S, int row, int quad) {
    int slot = ((row >> 1) + quad) & 3;
    return *(const short8*)(S + row * 32 + slot * 8);
}
// BK=64 tile: row stride 64, 8 slots of 16B
__device__ __forceinline__ short8 fragld64(const unsigned short* S, int row, int lp) {
    int slot = ((row >> 1) + lp) & 7;
    return *(const short8*)(S + row * 64 + slot * 8);
}
// f32 BK=32 tile: bf16 fragment for quad
__device__ __forceinline__ short8 fragldf(const float* S, int row, int quad) {
    int lp0 = quad * 2;
    int s0 = ((row >> 1) + lp0) & 7, s1 = ((row >> 1) + lp0 + 1) & 7;
    float4 a = *(const float4*)(S + row * 32 + s0 * 4);
    float4 b = *(const float4*)(S + row * 32 + s1 * 4);
    short8 r;
    r[0] = (short)f2bf(a.x); r[1] = (short)f2bf(a.y);
    r[2] = (short)f2bf(a.z); r[3] = (short)f2bf(a.w);
    r[4] = (short)f2bf(b.x); r[5] = (short)f2bf(b.y);
    r[6] = (short)f2bf(b.z); r[7] = (short)f2bf(b.w);
    return r;
}

// ---------------- merged prep: x-transpose + both weight casts ----------------
#define NWIN  (MPADIN*DIMC)
#define NWOUT (DIMC*KPAD)
__global__ __launch_bounds__(256) void k_prep(const float* __restrict__ x,
                                              const float* __restrict__ Win,
                                              const float* __restrict__ Wout,
                                              unsigned short* __restrict__ Xt,
                                              unsigned short* __restrict__ Wbin,
                                              unsigned short* __restrict__ Wbout) {
    int bid = blockIdx.x, tid = threadIdx.x;
    if (bid < 512) {                         // x [64][256][196] f32 -> Xt [64][196][256] bf16
        __shared__ float xs[32][197];
        int b = bid >> 3, c0 = (bid & 7) * 32;
        for (int i = tid; i < 32 * P; i += 256) {
            int ci = i / P, pp = i - ci * P;
            xs[ci][pp] = x[((size_t)b * DIMC + c0 + ci) * P + pp];
        }
        __syncthreads();
        for (int j = tid; j < P * 32; j += 256) {
            int ci = j & 31, pp = j >> 5;
            Xt[((size_t)b * P + pp) * DIMC + c0 + ci] = f2bf(xs[ci][pp]);
        }
    } else {                                 // vectorized weight casts
        int i = ((bid - 512) * 256 + tid) * 4;
        if (i < NWIN) {
            short4v s = (short4v)0;
            if (i < CHN * DIMC) {            // 348160 %4==0: group all-valid or all-pad
                float4 v = *(const float4*)(Win + i);
                s[0] = (short)f2bf(v.x); s[1] = (short)f2bf(v.y);
                s[2] = (short)f2bf(v.z); s[3] = (short)f2bf(v.w);
            }
            *(short4v*)(Wbin + i) = s;
        } else if (i < NWIN + NWOUT) {
            int j = i - NWIN;
            int o = j / KPAD, k = j - o * KPAD;
            short4v s = (short4v)0;
            if (k < HID) {                   // HID%4==0: group all-valid or all-pad
                float4 v = *(const float4*)(Wout + o * HID + k);
                s[0] = (short)f2bf(v.x); s[1] = (short)f2bf(v.y);
                s[2] = (short)f2bf(v.z); s[3] = (short)f2bf(v.w);
            }
            *(short4v*)(Wbout + j) = s;
        }
    }
}

// ---------------- fused weight-generator network (cooperative, 49 blocks) ----------------
__device__ __forceinline__ void block_partials(float s, float ss, float* red, float* redp, int tid, int blk) {
    #pragma unroll
    for (int off = 32; off > 0; off >>= 1) {
        s  += __shfl_down(s, off);
        ss += __shfl_down(ss, off);
    }
    int wid = tid >> 6;
    if ((tid & 63) == 0) { red[wid*2] = s; red[wid*2+1] = ss; }
    __syncthreads();
    if (tid == 0) {
        float S = 0.f, SS = 0.f;
        for (int i = 0; i < 4; i++) { S += red[i*2]; SS += red[i*2+1]; }
        redp[blk*2] = S; redp[blk*2+1] = SS;
    }
    __syncthreads();
}
__device__ __forceinline__ void ln_params(const float* redp, float& mu, float& rstd) {
    float S = 0.f, SS = 0.f;
    for (int i = 0; i < 49; i++) { S += redp[i*2]; SS += redp[i*2+1]; }
    mu = S / (float)(INTER*P);
    float var = SS / (float)(INTER*P) - mu*mu;
    rstd = rsqrtf(var + EPSLN);
}
__device__ __forceinline__ float conv64b(const float as[INTER][16][16], const float* __restrict__ w,
                                         int c, int y, int x) {
    float acc = 0.f;
    for (int ci = 0; ci < INTER; ci++) {
        const float* wr = w + (c*INTER + ci)*9;
        acc += wr[0]*as[ci][y  ][x] + wr[1]*as[ci][y  ][x+1] + wr[2]*as[ci][y  ][x+2]
             + wr[3]*as[ci][y+1][x] + wr[4]*as[ci][y+1][x+1] + wr[5]*as[ci][y+1][x+2]
             + wr[6]*as[ci][y+2][x] + wr[7]*as[ci][y+2][x+1] + wr[8]*as[ci][y+2][x+2];
    }
    return acc;
}
__device__ __forceinline__ void stage_plane(float as[INTER][16][16], const float* __restrict__ a, int tid) {
    for (int i = tid; i < INTER * 256; i += 256) {
        int c = i >> 8, r = i & 255, ly = r >> 4, lx = r & 15;
        float val = 0.f;
        if (ly >= 1 && ly <= HP && lx >= 1 && lx <= WP) val = a[c*P + (ly-1)*WP + (lx-1)];
        as[c][ly][lx] = val;
    }
    __syncthreads();
}

__global__ __launch_bounds__(256) void k_wgen(const float* __restrict__ posi,
                                              const float* __restrict__ w0, const float* __restrict__ g0, const float* __restrict__ b0,
                                              const float* __restrict__ w1, const float* __restrict__ g1, const float* __restrict__ b1,
                                              const float* __restrict__ w2, const float* __restrict__ g2, const float* __restrict__ b2,
                                              float* __restrict__ a, float* __restrict__ a2,
                                              float* __restrict__ redp, unsigned short* __restrict__ imc) {
    cg::grid_group grid = cg::this_grid();
    __shared__ __align__(16) float as[INTER][16][16];   // 64 KB
    __shared__ float red[8];
    int tid = threadIdx.x, blk = blockIdx.x;
    int gidx = blk * 256 + tid;                          // 0..12543, exactly covers INTER*P
    int c = gidx / P, p = gidx - c * P, y = p / WP, x = p - (p/WP)*WP;

    // ---- stage0: conv(posi,w0) ----
    for (int i = tid; i < POSI * 256; i += 256) {
        int cc = i >> 8, r = i & 255, ly = r >> 4, lx = r & 15;
        float v = 0.f;
        if (ly >= 1 && ly <= HP && lx >= 1 && lx <= WP) v = posi[cc*P + (ly-1)*WP + (lx-1)];
        as[cc][ly][lx] = v;
    }
    __syncthreads();
    float t = 0.f;
    #pragma unroll
    for (int ci = 0; ci < POSI; ci++)
        #pragma unroll
        for (int dy = 0; dy < 3; dy++)
            #pragma unroll
            for (int dx = 0; dx < 3; dx++)
                t += w0[((c*POSI + ci)*3 + dy)*3 + dx] * as[ci][y+dy][x+dx];
    block_partials(t, t*t, red, redp, tid, blk);
    grid.sync();                                         // #1: partials ready
    float mu, rstd;
    ln_params(redp, mu, rstd);
    float av = (t - mu) * rstd * g0[gidx] + b0[gidx];
    a[gidx] = av > 0.f ? av : 0.f;
    grid.sync();                                         // #2: a ready
    // ---- conv1 + LN1 ----
    stage_plane(as, a, tid);
    float v1 = conv64b(as, w1, c, y, x);
    block_partials(v1, v1*v1, red, redp + 128, tid, blk);
    grid.sync();                                         // #3
    ln_params(redp + 128, mu, rstd);
    av = (v1 - mu) * rstd * g1[gidx] + b1[gidx];
    a2[gidx] = av > 0.f ? av : 0.f;
    grid.sync();                                         // #4: a2 ready
    // ---- conv2 + LN2 ----
    stage_plane(as, a2, tid);
    float v2 = conv64b(as, w2, c, y, x);
    block_partials(v2, v2*v2, red, redp + 256, tid, blk);
    grid.sync();                                         // #5
    ln_params(redp + 256, mu, rstd);
    av = (v2 - mu) * rstd * g2[gidx] + b2[gidx];
    a[gidx] = av > 0.f ? av : 0.f;
    grid.sync();                                         // #6: final a ready
    // ---- im2col ----
    for (int idx = gidx; idx < P * KIM; idx += 49 * 256) {
        int pp = idx / KIM, q = idx - pp * KIM;
        int ci = q / 9, k = q - ci * 9;
        int yy = pp / WP + k / 3 - 1, xx = pp % WP + k % 3 - 1;
        float v = 0.f;
        if (yy >= 0 && yy < HP && xx >= 0 && xx < WP) v = a[ci * P + yy * WP + xx];
        imc[idx] = f2bf(v);
    }
}

// final conv as tiled MFMA GEMM; A staged DIRECTLY from wf (f32) with k-major row map.
__global__ __launch_bounds__(256) void k_gemm_wf(const float* __restrict__ wf,
                                                 const unsigned short* __restrict__ imc,
                                                 unsigned short* __restrict__ wgtT) {
    __shared__ __align__(16) unsigned short buf[P * 72];     // 28.2 KB
    float*          Asf = (float*)buf;                       // 64*32 f32 = 8 KB
    unsigned short* Bs  = buf + 4096;                        // 208*32 bf16 = 13 KB
    unsigned short* ot  = buf;                               // reused after K-loop
    int tid = threadIdx.x;
    int w = tid >> 6, lane = tid & 63, quad = lane >> 4, c16 = lane & 15;
    int m0 = blockIdx.x * 64;                                // 198 blocks
    int kk = m0 / MW, ch0 = m0 - kk * MW;                    // tile within one k-plane
    for (int i = tid; i < 48; i += 256)                      // zero Bs pad rows 196..207
        *(short8*)(Bs + 196 * 32 + i * 8) = (short8)0;
    f32x4 acc[13];
    #pragma unroll
    for (int f = 0; f < 13; f++) acc[f] = (f32x4)0.f;

    for (int kc = 0; kc < 18; ++kc) {
        int k0 = kc * 32;
        if (kc) __syncthreads();
        #pragma unroll
        for (int i = tid; i < 512; i += 256) {               // A: 64 rows x 8 f32-pieces
            int r = i >> 3, s = i & 7, q = (s - (r >> 1)) & 7;
            int ch = ch0 + r; if (ch >= CHN) ch = CHN - 1;   // clamp; discarded at store
            gl2lds16f(wf + (size_t)(ch * 9 + kk) * KIM + k0 + q * 4, Asf + (i & ~63) * 4);
        }
        for (int i = tid; i < 784; i += 256) {               // B: 196 rows x 4 pieces
            int r = i >> 2, s = i & 3, q = (s - (r >> 1)) & 3;
            gl2lds16(imc + (size_t)r * KIM + k0 + q * 8, Bs + (i & ~63) * 8);
        }
        __syncthreads();
        short8 af = fragldf(Asf, w * 16 + c16, quad);
        #pragma unroll
        for (int f = 0; f < 13; f++) {
            short8 bf = fragld(Bs, f * 16 + c16, quad);
            acc[f] = __builtin_amdgcn_mfma_f32_16x16x32_bf16(af, bf, acc[f], 0, 0, 0);
        }
    }
    __syncthreads();
    #pragma unroll
    for (int f = 0; f < 13; f++) {
        int p = f * 16 + c16;
        if (p < P) {
            short4v sv;
            sv[0] = (short)f2bf(acc[f][0]);
            sv[1] = (short)f2bf(acc[f][1]);
            sv[2] = (short)f2bf(acc[f][2]);
            sv[3] = (short)f2bf(acc[f][3]);
            *(short4v*)(ot + p * 72 + w * 16 + quad * 4) = sv;
        }
    }
    __syncthreads();
    int nvalid = CHN - ch0; if (nvalid > 64) nvalid = 64;
    for (int p = tid; p < P; p += 256) {
        const short8* src = (const short8*)(ot + p * 72);
        unsigned short* dst = wgtT + ((size_t)p * 9 + kk) * CHN + ch0;
        #pragma unroll
        for (int j = 0; j < 8; j++)
            if (j * 8 < nvalid) *(short8*)(dst + j * 8) = src[j];
    }
}

// ---------------- tiled MFMA GEMM 1 (BK=64): h1t[n][m] = sum_k Wbin[m][k] Xt[n][k] --------
__global__ __launch_bounds__(256) void k_gemm_in(const unsigned short* __restrict__ A,
                                                 const unsigned short* __restrict__ B,
                                                 unsigned short* __restrict__ C) {
    __shared__ __align__(16) unsigned short As[128 * 64];    // 16 KB
    __shared__ __align__(16) unsigned short Bs[128 * 64];    // 16 KB
    int tid = threadIdx.x;
    int w = tid >> 6, lane = tid & 63, quad = lane >> 4, c16 = lane & 15;
    int m0 = blockIdx.x * 128, n0 = blockIdx.y * 128;
    int wm = (w & 1) * 64, wn = (w >> 1) * 64;
    f32x4 acc[4][4];
    #pragma unroll
    for (int i = 0; i < 4; i++)
        #pragma unroll
        for (int j = 0; j < 4; j++) acc[i][j] = (f32x4)0.f;

    for (int kc = 0; kc < 4; ++kc) {                         // K=256, chunks of 64
        int k0 = kc * 64;
        if (kc) __syncthreads();
        #pragma unroll
        for (int i = tid; i < 1024; i += 256) {              // A: 128 rows x 8 pieces
            int r = i >> 3, s = i & 7, q = (s - (r >> 1)) & 7;
            gl2lds16(A + (size_t)(m0 + r) * DIMC + k0 + q * 8, As + (i & ~63) * 8);
        }
        #pragma unroll
        for (int i = tid; i < 1024; i += 256) {              // B: 128 rows x 8 pieces
            int r = i >> 3, s = i & 7, q = (s - (r >> 1)) & 7;
            gl2lds16(B + (size_t)(n0 + r) * DIMC + k0 + q * 8, Bs + (i & ~63) * 8);
        }
        __syncthreads();
        #pragma unroll
        for (int ks = 0; ks < 2; ++ks) {
            short8 af[4], bfr[4];
            #pragma unroll
            for (int i = 0; i < 4; i++) af[i] = fragld64(As, wm + i * 16 + c16, ks * 4 + quad);
            #pragma unroll
            for (int j = 0; j < 4; j++) bfr[j] = fragld64(Bs, wn + j * 16 + c16, ks * 4 + quad);
            #pragma unroll
            for (int i = 0; i < 4; i++)
                #pragma unroll
                for (int j = 0; j < 4; j++)
                    acc[i][j] = __builtin_amdgcn_mfma_f32_16x16x32_bf16(af[i], bfr[j], acc[i][j], 0, 0, 0);
        }
    }
    #pragma unroll
    for (int j = 0; j < 4; j++) {
        int n = n0 + wn + j * 16 + c16;
        unsigned short* dst = C + (size_t)n * CHN;
        #pragma unroll
        for (int i = 0; i < 4; i++) {
            int m = m0 + wm + i * 16 + quad * 4;
            if (m < CHN) {
                short4v sv;
                sv[0] = (short)f2bf(acc[i][j][0]);
                sv[1] = (short)f2bf(acc[i][j][1]);
                sv[2] = (short)f2bf(acc[i][j][2]);
                sv[3] = (short)f2bf(acc[i][j][3]);
                *(short4v*)(dst + m) = sv;
            }
        }
    }
}

// ---------------- fused tvconv + gelu-gate: XCD-affinity swizzled grid ----------------
__global__ __launch_bounds__(256) void k_tvg(const unsigned short* __restrict__ h1t,
                                             const unsigned short* __restrict__ wgtT,
                                             unsigned short* __restrict__ hgt) {
    __shared__ __align__(16) unsigned short wl[9 * CHN];   // 24480 B, [k][CHN]
    int id = blockIdx.x;
    int xcd = id & 7, q = id >> 3;
    int p = xcd * 25 + (q % 25);
    int bg = q / 25;
    if (p >= P) return;
    int b0 = bg * 16, tid = threadIdx.x;
    const unsigned short* wrow = wgtT + (size_t)p * 9 * CHN;
    for (int i = tid * 8; i < 9 * CHN; i += 256 * 8)
        *(short8*)(wl + i) = *(const short8*)(wrow + i);
    int y = p / WP, x = p - (p / WP) * WP;
    int pn[9]; bool pv[9];
    #pragma unroll
    for (int k = 0; k < 9; k++) {
        int yy = y + k / 3 - 1, xx = x + (k % 3) - 1;
        pv[k] = (yy >= 0 && yy < HP && xx >= 0 && xx < WP);
        pn[k] = pv[k] ? yy * WP + xx : 0;
    }
    __syncthreads();
    for (int j = tid; j < 16 * 85; j += 256) {
        int bl = j / 85, c = (j - bl * 85) * 8;
        int b = b0 + bl;
        const unsigned short* hb = h1t + (size_t)b * P * CHN;
        float s1[8], s2[8];
        #pragma unroll
        for (int e = 0; e < 8; e++) { s1[e] = 0.f; s2[e] = 0.f; }
        #pragma unroll
        for (int k = 0; k < 9; k++) {
            if (!pv[k]) continue;
            const unsigned short* hr = hb + (size_t)pn[k] * CHN + c;
            short8 h1v = *(const short8*)hr;
            short8 h2v = *(const short8*)(hr + HID);
            short8 w1v = *(const short8*)(wl + k * CHN + c);
            short8 w2v = *(const short8*)(wl + k * CHN + HID + c);
            #pragma unroll
            for (int e = 0; e < 8; e++) {
                s1[e] += bf2f((unsigned short)w1v[e]) * bf2f((unsigned short)h1v[e]);
                s2[e] += bf2f((unsigned short)w2v[e]) * bf2f((unsigned short)h2v[e]);
            }
        }
        short8 o;
        #pragma unroll
        for (int e = 0; e < 8; e++) {
            float gl = 0.5f * s1[e] * (1.f + erff(s1[e] * 0.70710678118654752f));
            o[e] = (short)f2bf(gl * s2[e]);
        }
        *(short8*)(hgt + ((size_t)b * P + p) * KPAD + c) = o;
    }
    if (tid < 48) {
        int bl = tid / 3, z = (tid - bl * 3) * 8;
        *(short8*)(hgt + ((size_t)(b0 + bl) * P + p) * KPAD + HID + z) = (short8)0;
    }
}

// ---------------- tiled MFMA GEMM 2 (BK=64): out[m][n] = sum_k Wbout[m][k] hgt[n][k] ------
__global__ __launch_bounds__(256) void k_gemm_out(const unsigned short* __restrict__ A,
                                                  const unsigned short* __restrict__ B,
                                                  float* __restrict__ out) {
    __shared__ __align__(16) unsigned short As[64 * 64];     // 8 KB
    __shared__ __align__(16) unsigned short Bs[128 * 64];    // 16 KB
    int tid = threadIdx.x;
    int w = tid >> 6, lane = tid & 63, quad = lane >> 4, c16 = lane & 15;
    int m0 = blockIdx.x * 64, n0 = blockIdx.y * 128;
    int wm = (w & 1) * 32, wn = (w >> 1) * 64;
    f32x4 acc[2][4];
    #pragma unroll
    for (int i = 0; i < 2; i++)
        #pragma unroll
        for (int j = 0; j < 4; j++) acc[i][j] = (f32x4)0.f;

    for (int kc = 0; kc < 11; ++kc) {                        // K=704, chunks of 64
        int k0 = kc * 64;
        if (kc) __syncthreads();
        #pragma unroll
        for (int i = tid; i < 512; i += 256) {               // A: 64 rows x 8 pieces
            int r = i >> 3, s = i & 7, q = (s - (r >> 1)) & 7;
            gl2lds16(A + (size_t)(m0 + r) * KPAD + k0 + q * 8, As + (i & ~63) * 8);
        }
        #pragma unroll
        for (int i = tid; i < 1024; i += 256) {              // B: 128 rows x 8 pieces
            int r = i >> 3, s = i & 7, q = (s - (r >> 1)) & 7;
            gl2lds16(B + (size_t)(n0 + r) * KPAD + k0 + q * 8, Bs + (i & ~63) * 8);
        }
        __syncthreads();
        #pragma unroll
        for (int ks = 0; ks < 2; ++ks) {
            short8 af[2], bfr[4];
            #pragma unroll
            for (int i = 0; i < 2; i++) af[i] = fragld64(As, wm + i * 16 + c16, ks * 4 + quad);
            #pragma unroll
            for (int j = 0; j < 4; j++) bfr[j] = fragld64(Bs, wn + j * 16 + c16, ks * 4 + quad);
            #pragma unroll
            for (int i = 0; i < 2; i++)
                #pragma unroll
                for (int j = 0; j < 4; j++)
                    acc[i][j] = __builtin_amdgcn_mfma_f32_16x16x32_bf16(af[i], bfr[j], acc[i][j], 0, 0, 0);
        }
    }
    #pragma unroll
    for (int j = 0; j < 4; j++) {
        int n = n0 + wn + j * 16 + c16;
        int b = n / P, pp = n - b * P;
        #pragma unroll
        for (int i = 0; i < 2; i++) {
            int m = m0 + wm + i * 16 + quad * 4;
            #pragma unroll
            for (int r = 0; r < 4; r++)
                out[((size_t)b * DIMC + m + r) * P + pp] = acc[i][j][r];
        }
    }
}

extern "C" void kernel_launch(void* const* d_in, const int* in_sizes, int n_in,
                              void* d_out, int out_size, void* d_ws, size_t ws_size,
                              hipStream_t stream) {
    (void)in_sizes; (void)n_in; (void)out_size; (void)ws_size;
    const float* x     = (const float*)d_in[0];
    const float* W_in  = (const float*)d_in[1];
    const float* posi  = (const float*)d_in[2];
    const float* w0    = (const float*)d_in[3];
    const float* g0    = (const float*)d_in[4];
    const float* b0    = (const float*)d_in[5];
    const float* w1    = (const float*)d_in[6];
    const float* g1    = (const float*)d_in[7];
    const float* b1    = (const float*)d_in[8];
    const float* w2    = (const float*)d_in[9];
    const float* g2    = (const float*)d_in[10];
    const float* b2    = (const float*)d_in[11];
    const float* wf    = (const float*)d_in[12];
    const float* W_out = (const float*)d_in[13];
    float* out = (float*)d_out;
    char* ws = (char*)d_ws;

    unsigned short* Wbin  = (unsigned short*)(ws + OFS_WBIN);
    unsigned short* Wbout = (unsigned short*)(ws + OFS_WBOUT);
    unsigned short* Xt    = (unsigned short*)(ws + OFS_XT);
    float*          a_buf = (float*)(ws + OFS_ABUF);
    float*          a2buf = (float*)(ws + OFS_A2BUF);
    float*          redp  = (float*)(ws + OFS_RED);
    unsigned short* wgtT  = (unsigned short*)(ws + OFS_WGTT);
    unsigned short* h1t   = (unsigned short*)(ws + OFS_H1T);
    unsigned short* hgt   = (unsigned short*)(ws + OFS_HGT);
    unsigned short* imc   = (unsigned short*)(ws + OFS_IMC);

    // prep: x transpose + weight casts (one launch)
    k_prep<<<1040, 256, 0, stream>>>(x, W_in, W_out, Xt, Wbin, Wbout);

    // weight-generator network: one cooperative launch (49 blocks, 6 grid syncs)
    void* kargs[] = {(void*)&posi, (void*)&w0, (void*)&g0, (void*)&b0,
                     (void*)&w1, (void*)&g1, (void*)&b1,
                     (void*)&w2, (void*)&g2, (void*)&b2,
                     (void*)&a_buf, (void*)&a2buf, (void*)&redp, (void*)&imc};
    hipLaunchCooperativeKernel((void*)k_wgen, dim3(49), dim3(256), kargs, 0, stream);

    k_gemm_wf<<<MTOT/64, 256, 0, stream>>>(wf, imc, wgtT);

    // main path (tiled MFMA, BK=64)
    k_gemm_in <<<dim3(MPADIN/128, (BATCH*P)/128), 256, 0, stream>>>(Wbin, Xt, h1t);
    k_tvg     <<<800, 256, 0, stream>>>(h1t, wgtT, hgt);
    k_gemm_out<<<dim3(DIMC/64, (BATCH*P)/128), 256, 0, stream>>>(Wbout, hgt, out);
}